// Round 4
// baseline (521.533 us; speedup 1.0000x reference)
//
#include <hip/hip_runtime.h>
#include <math.h>

// N=50000 nodes, E0=800000 edges (+N self loops), IN=128, H=8, C=8 (HC=64), ED=16, T=96

struct __align__(8) US4 { unsigned short x, y, z, w; };

__device__ __forceinline__ unsigned short f2bf(float f) {
    unsigned u = __float_as_uint(f);
    unsigned r = (u + 0x7fffu + ((u >> 16) & 1u)) >> 16;
    return (unsigned short)r;
}
__device__ __forceinline__ float bf2f(unsigned short u) {
    return __uint_as_float(((unsigned)u) << 16);
}
__device__ __forceinline__ float ftanh(float x) {
    float e = __expf(2.f * x);
    return 1.f - 2.f / (e + 1.f);
}

// ---------------- node projections: q (f32), k,v (bf16), a_node,b_node (f32) ----------------
// 256 threads / 64 nodes; thread = (node-quarter sh, col-quad cq): 4 cols x 16 nodes each.
__global__ __launch_bounds__(256) void k_proj(
    const float* __restrict__ x,
    const float* __restrict__ Wq, const float* __restrict__ Wk, const float* __restrict__ Wv,
    const float* __restrict__ compW,
    float* __restrict__ q, unsigned short* __restrict__ kb, unsigned short* __restrict__ vb,
    float* __restrict__ an, float* __restrict__ bn, int N)
{
    __shared__ float xt[64 * 128];
    const int n0 = blockIdx.x * 64;
    const int tid = threadIdx.x;
    for (int i = tid; i < 2048; i += 256) {
        int row = i >> 5, c4 = i & 31;
        int n = n0 + row;
        float4 val = make_float4(0.f, 0.f, 0.f, 0.f);
        if (n < N) val = ((const float4*)(x + (size_t)n * 128))[c4];
        ((float4*)xt)[i] = val;
    }
    __syncthreads();
    if (tid >= 208) return;
    const int sh = tid / 52;          // node quarter (16 nodes)
    const int cq = tid % 52;          // column quad

    const float* wrow; int wstride;
    if (cq < 16)      { wrow = Wq + (size_t)cq * 4 * 128;          wstride = 128; }
    else if (cq < 32) { wrow = Wk + (size_t)(cq - 16) * 4 * 128;   wstride = 128; }
    else if (cq < 48) { wrow = Wv + (size_t)(cq - 32) * 4 * 128;   wstride = 128; }
    else if (cq < 50) { wrow = compW + (size_t)(cq - 48) * 4 * 256;       wstride = 256; }
    else              { wrow = compW + (size_t)(cq - 50) * 4 * 256 + 128; wstride = 256; }

    float acc[16][4];
    #pragma unroll
    for (int i = 0; i < 16; i++)
        #pragma unroll
        for (int j = 0; j < 4; j++) acc[i][j] = 0.f;

    const float4* xt4 = (const float4*)xt;
    for (int k4 = 0; k4 < 32; k4++) {
        float4 w0 = ((const float4*)(wrow + 0 * wstride))[k4];
        float4 w1 = ((const float4*)(wrow + 1 * wstride))[k4];
        float4 w2 = ((const float4*)(wrow + 2 * wstride))[k4];
        float4 w3 = ((const float4*)(wrow + 3 * wstride))[k4];
        #pragma unroll
        for (int nn = 0; nn < 16; nn++) {
            float4 x4 = xt4[(sh * 16 + nn) * 32 + k4];
            acc[nn][0] += x4.x * w0.x + x4.y * w0.y + x4.z * w0.z + x4.w * w0.w;
            acc[nn][1] += x4.x * w1.x + x4.y * w1.y + x4.z * w1.z + x4.w * w1.w;
            acc[nn][2] += x4.x * w2.x + x4.y * w2.y + x4.z * w2.z + x4.w * w2.w;
            acc[nn][3] += x4.x * w3.x + x4.y * w3.y + x4.z * w3.z + x4.w * w3.w;
        }
    }
    #pragma unroll
    for (int nn = 0; nn < 16; nn++) {
        int n = n0 + sh * 16 + nn;
        if (n >= N) continue;
        if (cq < 16) {
            float4 r = make_float4(acc[nn][0], acc[nn][1], acc[nn][2], acc[nn][3]);
            ((float4*)(q + (size_t)n * 64))[cq] = r;
        } else if (cq < 32) {
            US4 u = { f2bf(acc[nn][0]), f2bf(acc[nn][1]), f2bf(acc[nn][2]), f2bf(acc[nn][3]) };
            ((US4*)(kb + (size_t)n * 64))[cq - 16] = u;
        } else if (cq < 48) {
            US4 u = { f2bf(acc[nn][0]), f2bf(acc[nn][1]), f2bf(acc[nn][2]), f2bf(acc[nn][3]) };
            ((US4*)(vb + (size_t)n * 64))[cq - 32] = u;
        } else if (cq < 50) {
            float4 r = make_float4(acc[nn][0], acc[nn][1], acc[nn][2], acc[nn][3]);
            ((float4*)(an + (size_t)n * 8))[cq - 48] = r;
        } else {
            float4 r = make_float4(acc[nn][0], acc[nn][1], acc[nn][2], acc[nn][3]);
            ((float4*)(bn + (size_t)n * 8))[cq - 50] = r;
        }
    }
}

// ---------------- temporal profile normalization (ddof=1) -> bf16, one wave per node ----------
__global__ __launch_bounds__(256) void k_tpn(const float* __restrict__ tp,
                                             unsigned short* __restrict__ tpnb, int N)
{
    int wave = threadIdx.x >> 6;
    int lane = threadIdx.x & 63;
    int n = blockIdx.x * 4 + wave;
    if (n >= N) return;
    const float* row = tp + (size_t)n * 96;
    float v0 = row[lane];
    float v1 = (lane < 32) ? row[64 + lane] : 0.f;
    float s = v0 + v1, ss = v0 * v0 + v1 * v1;
    #pragma unroll
    for (int m = 1; m < 64; m <<= 1) { s += __shfl_xor(s, m); ss += __shfl_xor(ss, m); }
    float mean = s * (1.f / 96.f);
    float var = (ss - 96.f * mean * mean) * (1.f / 95.f);
    var = fmaxf(var, 0.f);
    float inv = 1.f / (sqrtf(var) + 1e-8f);
    unsigned short* orow = tpnb + (size_t)n * 96;
    orow[lane] = f2bf((v0 - mean) * inv);
    if (lane < 32) orow[64 + lane] = f2bf((v1 - mean) * inv);
}

// ---------------- CSR build: histogram / scan / scatter ----------------
__global__ __launch_bounds__(256) void k_hist(const int* __restrict__ ei,
                                              int* __restrict__ deg, int E0, int N)
{
    int e = blockIdx.x * 256 + threadIdx.x;
    int E = E0 + N;
    if (e >= E) return;
    int dst = (e < E0) ? ei[E0 + e] : (e - E0);
    atomicAdd(&deg[dst], 1);
}

__global__ __launch_bounds__(1024) void k_scan(const int* __restrict__ deg,
                                               int* __restrict__ row,
                                               int* __restrict__ cursor, int N)
{
    __shared__ int part[1024];
    int t = threadIdx.x;
    int chunk = (N + 1023) >> 10;
    int s0 = t * chunk;
    int s = 0;
    for (int i = 0; i < chunk; i++) {
        int idx = s0 + i;
        if (idx < N) s += deg[idx];
    }
    part[t] = s;
    __syncthreads();
    for (int off = 1; off < 1024; off <<= 1) {
        int vv = (t >= off) ? part[t - off] : 0;
        __syncthreads();
        part[t] += vv;
        __syncthreads();
    }
    int run = (t == 0) ? 0 : part[t - 1];
    for (int i = 0; i < chunk; i++) {
        int idx = s0 + i;
        if (idx < N) { row[idx] = run; cursor[idx] = run; run += deg[idx]; }
    }
    if (t == 1023) row[N] = part[1023];
}

__global__ __launch_bounds__(256) void k_scatter(const int* __restrict__ ei,
                                                 int* __restrict__ cursor,
                                                 int2* __restrict__ csrp, int E0, int N)
{
    int e = blockIdx.x * 256 + threadIdx.x;
    int E = E0 + N;
    if (e >= E) return;
    int src, dst;
    if (e < E0) { src = ei[e]; dst = ei[E0 + e]; }
    else        { src = e - E0; dst = src; }
    int pos = atomicAdd(&cursor[dst], 1);
    csrp[pos] = make_int2(e, src);
}

// ---------------- edge precompute: ext[e][h] = efk(e,h) - 0.25*learned(e) ----------------
// 8 lanes per edge (lane = head); edges in original order -> eattr/ei sequential.
__global__ __launch_bounds__(256) void k_edge_pre(
    const int* __restrict__ ei, const float* __restrict__ eattr,
    const unsigned short* __restrict__ kb,
    const float* __restrict__ an, const float* __restrict__ bn,
    const float* __restrict__ We, const float* __restrict__ comp_b,
    float* __restrict__ ext, int E0, int N)
{
    __shared__ float WeT[16 * 64];                    // [d][hc]
    const int tid = threadIdx.x;
    for (int i = tid; i < 1024; i += 256)
        WeT[i] = We[(i & 63) * 16 + (i >> 6)];
    __syncthreads();
    const int E = E0 + N;
    const int e = blockIdx.x * 32 + (tid >> 3);
    if (e >= E) return;
    const int h = tid & 7;
    int s, dn;
    if (e < E0) { s = ei[e]; dn = ei[E0 + e]; }
    else        { s = e - E0; dn = s; }

    // k fragment (head h of src), bf16
    float kr[8];
    {
        const US4* kp = (const US4*)(kb + (size_t)s * 64 + h * 8);
        US4 k0 = kp[0], k1 = kp[1];
        kr[0] = bf2f(k0.x); kr[1] = bf2f(k0.y); kr[2] = bf2f(k0.z); kr[3] = bf2f(k0.w);
        kr[4] = bf2f(k1.x); kr[5] = bf2f(k1.y); kr[6] = bf2f(k1.z); kr[7] = bf2f(k1.w);
    }
    float ear[16];
    if (e < E0) {
        const float4* ep = (const float4*)(eattr + (size_t)e * 16);
        #pragma unroll
        for (int i = 0; i < 4; i++) {
            float4 pa = ep[i];
            ear[i * 4] = pa.x; ear[i * 4 + 1] = pa.y; ear[i * 4 + 2] = pa.z; ear[i * 4 + 3] = pa.w;
        }
    } else {
        #pragma unroll
        for (int i = 0; i < 16; i++) ear[i] = 1.f;
    }

    float efk = 0.f;
    #pragma unroll
    for (int d = 0; d < 16; d++) {
        float kw = 0.f;
        #pragma unroll
        for (int c = 0; c < 8; c++) kw += WeT[d * 64 + h * 8 + c] * kr[c];
        efk += ear[d] * kw;
    }

    float t = ftanh(an[(size_t)s * 8 + h] + bn[(size_t)dn * 8 + h] + comp_b[h]);
    float tsum = t;
    tsum += __shfl_xor(tsum, 1); tsum += __shfl_xor(tsum, 2); tsum += __shfl_xor(tsum, 4);
    ext[(size_t)e * 8 + h] = efk - tsum * (0.25f / 8.f);
}

// ---------------- fused per-node: qk + corr + online softmax + aggregation + Wo ------------
// one wave per node; lane = h*8 + c
__global__ __launch_bounds__(256) void k_fused(
    const int2* __restrict__ csrp, const int* __restrict__ row,
    const unsigned short* __restrict__ tpnb, const float* __restrict__ q,
    const unsigned short* __restrict__ kb, const unsigned short* __restrict__ vb,
    const float* __restrict__ ext,
    const float* __restrict__ Wo, const float* __restrict__ bo,
    float* __restrict__ out, int E0, int N)
{
    const int tid = threadIdx.x;
    const int wave = tid >> 6, lane = tid & 63;
    const int h = lane >> 3;
    const int n = blockIdx.x * 4 + wave;
    if (n >= N) return;

    const int beg = row[n], end = row[n + 1];
    const float qv = q[(size_t)n * 64 + lane] * 0.35355339059327373f;  // 1/sqrt(8) folded
    float td0 = 0.f, td1 = 0.f;
    if (lane < 48) {
        unsigned u = *(const unsigned*)(tpnb + (size_t)n * 96 + 2 * lane);
        td0 = __uint_as_float(u << 16);
        td1 = __uint_as_float(u & 0xffff0000u);
    }

    float mh = -1e30f, dsum = 0.f, acc = 0.f;

    int2 ec = csrp[beg];
    for (int idx = beg; idx < end; ++idx) {
        const int e = ec.x, s = ec.y;
        // gathers (src side)
        unsigned tsu = 0;
        if (lane < 48) tsu = *(const unsigned*)(tpnb + (size_t)s * 96 + 2 * lane);
        unsigned short ku = kb[(size_t)s * 64 + lane];
        unsigned short vu = vb[(size_t)s * 64 + lane];
        float eh = ext[(size_t)e * 8 + h];
        if (idx + 1 < end) ec = csrp[idx + 1];   // prefetch next edge ids

        float ts0 = __uint_as_float(tsu << 16);
        float ts1 = __uint_as_float(tsu & 0xffff0000u);
        float cp = ts0 * td0 + ts1 * td1;          // corr partial
        float s1 = bf2f(ku) * qv;                  // qk partial (scaled)

        s1 += __shfl_xor(s1, 1); s1 += __shfl_xor(s1, 2); s1 += __shfl_xor(s1, 4);
        cp += __shfl_xor(cp, 1); cp += __shfl_xor(cp, 2); cp += __shfl_xor(cp, 4);
        cp += __shfl_xor(cp, 8); cp += __shfl_xor(cp, 16); cp += __shfl_xor(cp, 32);

        float a = s1 + eh - cp * (0.25f / 96.f);
        a = (a >= 0.f) ? a : 0.2f * a;             // leaky relu

        // online softmax update (per head, replicated across c)
        float mn = fmaxf(mh, a);
        float sc = __expf(mh - mn);
        float p = __expf(a - mn);
        dsum = dsum * sc + p;
        acc = acc * sc + p * bf2f(vu);
        mh = mn;
    }

    float outv = acc / (dsum + 1e-16f);

    // fused output projection: out[n][cp] = sum_hc outv[hc]*Wo[cp][hc] + bo[cp]
    float po[8];
    #pragma unroll
    for (int cp8 = 0; cp8 < 8; cp8++) po[cp8] = outv * Wo[cp8 * 64 + lane];
    #pragma unroll
    for (int m = 1; m < 64; m <<= 1) {
        #pragma unroll
        for (int cp8 = 0; cp8 < 8; cp8++) po[cp8] += __shfl_xor(po[cp8], m);
    }
    if (lane < 8) out[(size_t)n * 8 + lane] = po[lane] + bo[lane];
}

extern "C" void kernel_launch(void* const* d_in, const int* in_sizes, int n_in,
                              void* d_out, int out_size, void* d_ws, size_t ws_size,
                              hipStream_t stream)
{
    const float* x     = (const float*)d_in[0];
    const int*   ei    = (const int*)d_in[1];
    const float* eattr = (const float*)d_in[2];
    const float* tp    = (const float*)d_in[3];
    const float* Wq    = (const float*)d_in[4];
    const float* Wk    = (const float*)d_in[5];
    const float* Wv    = (const float*)d_in[6];
    const float* We    = (const float*)d_in[7];
    const float* compW = (const float*)d_in[8];
    const float* compb = (const float*)d_in[9];
    const float* Wo    = (const float*)d_in[10];
    const float* bo    = (const float*)d_in[11];
    float* out = (float*)d_out;

    const int N  = in_sizes[0] / 128;
    const int E0 = in_sizes[1] / 2;
    const int E  = E0 + N;

    float* ws = (float*)d_ws;
    size_t off = 0;
    unsigned short* tpnb = (unsigned short*)(ws + off); off += (size_t)N * 48;   // N*96 ushort
    float* q  = ws + off; off += (size_t)N * 64;
    unsigned short* kb = (unsigned short*)(ws + off); off += (size_t)N * 32;     // N*64 ushort
    unsigned short* vb = (unsigned short*)(ws + off); off += (size_t)N * 32;
    float* an = ws + off; off += (size_t)N * 8;
    float* bn = ws + off; off += (size_t)N * 8;
    float* ext = ws + off; off += (size_t)E * 8;
    int* deg    = (int*)(ws + off); off += N;
    int* rowp   = (int*)(ws + off); off += N + 1;
    int* cursor = (int*)(ws + off); off += N;
    int2* csrp  = (int2*)(ws + off); off += (size_t)E * 2;

    hipMemsetAsync(deg, 0, (size_t)N * sizeof(int), stream);

    k_hist<<<(E + 255) / 256, 256, 0, stream>>>(ei, deg, E0, N);
    k_scan<<<1, 1024, 0, stream>>>(deg, rowp, cursor, N);
    k_scatter<<<(E + 255) / 256, 256, 0, stream>>>(ei, cursor, csrp, E0, N);

    k_proj<<<(N + 63) / 64, 256, 0, stream>>>(x, Wq, Wk, Wv, compW, q, kb, vb, an, bn, N);
    k_tpn<<<(N + 3) / 4, 256, 0, stream>>>(tp, tpnb, N);
    k_edge_pre<<<(E + 31) / 32, 256, 0, stream>>>(ei, eattr, kb, an, bn, We, compb, ext, E0, N);
    k_fused<<<(N + 3) / 4, 256, 0, stream>>>(csrp, rowp, tpnb, q, kb, vb, ext, Wo, bo,
                                             out, E0, N);
}

// Round 5
// 363.789 us; speedup vs baseline: 1.4336x; 1.4336x over previous
//
#include <hip/hip_runtime.h>
#include <math.h>

// N=50000 nodes, E0=800000 edges (+N self loops), IN=128, H=8, C=8 (HC=64), ED=16, T=96

struct __align__(8) US4 { unsigned short x, y, z, w; };

__device__ __forceinline__ unsigned short f2bf(float f) {
    unsigned u = __float_as_uint(f);
    unsigned r = (u + 0x7fffu + ((u >> 16) & 1u)) >> 16;
    return (unsigned short)r;
}
__device__ __forceinline__ float bf2f(unsigned short u) {
    return __uint_as_float(((unsigned)u) << 16);
}

// ---------------- node projections: q (f32), k,v (bf16), a_node,b_node (f32) ----------------
__global__ __launch_bounds__(256) void k_proj(
    const float* __restrict__ x,
    const float* __restrict__ Wq, const float* __restrict__ Wk, const float* __restrict__ Wv,
    const float* __restrict__ compW,
    float* __restrict__ q, unsigned short* __restrict__ kb, unsigned short* __restrict__ vb,
    float* __restrict__ an, float* __restrict__ bn, int N)
{
    __shared__ float xt[64 * 128];
    const int n0 = blockIdx.x * 64;
    const int tid = threadIdx.x;
    for (int i = tid; i < 2048; i += 256) {
        int row = i >> 5, c4 = i & 31;
        int n = n0 + row;
        float4 val = make_float4(0.f, 0.f, 0.f, 0.f);
        if (n < N) val = ((const float4*)(x + (size_t)n * 128))[c4];
        ((float4*)xt)[i] = val;
    }
    __syncthreads();
    if (tid >= 208) return;
    const int sh = tid / 52;          // node quarter (16 nodes)
    const int cq = tid % 52;          // column quad

    const float* wrow; int wstride;
    if (cq < 16)      { wrow = Wq + (size_t)cq * 4 * 128;          wstride = 128; }
    else if (cq < 32) { wrow = Wk + (size_t)(cq - 16) * 4 * 128;   wstride = 128; }
    else if (cq < 48) { wrow = Wv + (size_t)(cq - 32) * 4 * 128;   wstride = 128; }
    else if (cq < 50) { wrow = compW + (size_t)(cq - 48) * 4 * 256;       wstride = 256; }
    else              { wrow = compW + (size_t)(cq - 50) * 4 * 256 + 128; wstride = 256; }

    float acc[16][4];
    #pragma unroll
    for (int i = 0; i < 16; i++)
        #pragma unroll
        for (int j = 0; j < 4; j++) acc[i][j] = 0.f;

    const float4* xt4 = (const float4*)xt;
    for (int k4 = 0; k4 < 32; k4++) {
        float4 w0 = ((const float4*)(wrow + 0 * wstride))[k4];
        float4 w1 = ((const float4*)(wrow + 1 * wstride))[k4];
        float4 w2 = ((const float4*)(wrow + 2 * wstride))[k4];
        float4 w3 = ((const float4*)(wrow + 3 * wstride))[k4];
        #pragma unroll
        for (int nn = 0; nn < 16; nn++) {
            float4 x4 = xt4[(sh * 16 + nn) * 32 + k4];
            acc[nn][0] += x4.x * w0.x + x4.y * w0.y + x4.z * w0.z + x4.w * w0.w;
            acc[nn][1] += x4.x * w1.x + x4.y * w1.y + x4.z * w1.z + x4.w * w1.w;
            acc[nn][2] += x4.x * w2.x + x4.y * w2.y + x4.z * w2.z + x4.w * w2.w;
            acc[nn][3] += x4.x * w3.x + x4.y * w3.y + x4.z * w3.z + x4.w * w3.w;
        }
    }
    #pragma unroll
    for (int nn = 0; nn < 16; nn++) {
        int n = n0 + sh * 16 + nn;
        if (n >= N) continue;
        if (cq < 16) {
            float4 r = make_float4(acc[nn][0], acc[nn][1], acc[nn][2], acc[nn][3]);
            ((float4*)(q + (size_t)n * 64))[cq] = r;
        } else if (cq < 32) {
            US4 u = { f2bf(acc[nn][0]), f2bf(acc[nn][1]), f2bf(acc[nn][2]), f2bf(acc[nn][3]) };
            ((US4*)(kb + (size_t)n * 64))[cq - 16] = u;
        } else if (cq < 48) {
            US4 u = { f2bf(acc[nn][0]), f2bf(acc[nn][1]), f2bf(acc[nn][2]), f2bf(acc[nn][3]) };
            ((US4*)(vb + (size_t)n * 64))[cq - 32] = u;
        } else if (cq < 50) {
            float4 r = make_float4(acc[nn][0], acc[nn][1], acc[nn][2], acc[nn][3]);
            ((float4*)(an + (size_t)n * 8))[cq - 48] = r;
        } else {
            float4 r = make_float4(acc[nn][0], acc[nn][1], acc[nn][2], acc[nn][3]);
            ((float4*)(bn + (size_t)n * 8))[cq - 50] = r;
        }
    }
}

// ---------------- temporal profile normalization (ddof=1) -> bf16, one wave per node ----------
__global__ __launch_bounds__(256) void k_tpn(const float* __restrict__ tp,
                                             unsigned short* __restrict__ tpnb, int N)
{
    int wave = threadIdx.x >> 6;
    int lane = threadIdx.x & 63;
    int n = blockIdx.x * 4 + wave;
    if (n >= N) return;
    const float* row = tp + (size_t)n * 96;
    float v0 = row[lane];
    float v1 = (lane < 32) ? row[64 + lane] : 0.f;
    float s = v0 + v1, ss = v0 * v0 + v1 * v1;
    #pragma unroll
    for (int m = 1; m < 64; m <<= 1) { s += __shfl_xor(s, m); ss += __shfl_xor(ss, m); }
    float mean = s * (1.f / 96.f);
    float var = (ss - 96.f * mean * mean) * (1.f / 95.f);
    var = fmaxf(var, 0.f);
    float inv = 1.f / (sqrtf(var) + 1e-8f);
    unsigned short* orow = tpnb + (size_t)n * 96;
    orow[lane] = f2bf((v0 - mean) * inv);
    if (lane < 32) orow[64 + lane] = f2bf((v1 - mean) * inv);
}

// ---------------- CSR build: histogram / 3-stage scan / scatter ----------------
__global__ __launch_bounds__(256) void k_hist(const int* __restrict__ ei,
                                              int* __restrict__ deg, int E0, int N)
{
    int e = blockIdx.x * 256 + threadIdx.x;
    int E = E0 + N;
    if (e >= E) return;
    int dst = (e < E0) ? ei[E0 + e] : (e - E0);
    atomicAdd(&deg[dst], 1);
}

__global__ __launch_bounds__(256) void k_scanA(const int* __restrict__ deg,
                                               int* __restrict__ bsum, int N)
{
    __shared__ int sm[256];
    int i = blockIdx.x * 256 + threadIdx.x;
    sm[threadIdx.x] = (i < N) ? deg[i] : 0;
    __syncthreads();
    for (int off = 128; off > 0; off >>= 1) {
        if (threadIdx.x < off) sm[threadIdx.x] += sm[threadIdx.x + off];
        __syncthreads();
    }
    if (threadIdx.x == 0) bsum[blockIdx.x] = sm[0];
}

// exclusive scan of NB (<=256) block sums, single block
__global__ __launch_bounds__(256) void k_scanB(int* __restrict__ bsum, int NB)
{
    __shared__ int sm[256];
    int t = threadIdx.x;
    sm[t] = (t < NB) ? bsum[t] : 0;
    __syncthreads();
    for (int off = 1; off < 256; off <<= 1) {
        int v = (t >= off) ? sm[t - off] : 0;
        __syncthreads();
        sm[t] += v;
        __syncthreads();
    }
    if (t < NB) bsum[t] = (t == 0) ? 0 : sm[t - 1];
}

__global__ __launch_bounds__(256) void k_scanC(const int* __restrict__ deg,
                                               const int* __restrict__ bsum,
                                               int* __restrict__ row,
                                               int* __restrict__ cursor, int N)
{
    __shared__ int sm[256];
    int b = blockIdx.x, t = threadIdx.x, i = b * 256 + t;
    int v = (i < N) ? deg[i] : 0;
    sm[t] = v;
    __syncthreads();
    for (int off = 1; off < 256; off <<= 1) {
        int u = (t >= off) ? sm[t - off] : 0;
        __syncthreads();
        sm[t] += u;
        __syncthreads();
    }
    int excl = bsum[b] + sm[t] - v;
    if (i < N) {
        row[i] = excl;
        cursor[i] = excl;
        if (i == N - 1) row[N] = excl + v;
    }
}

__global__ __launch_bounds__(256) void k_scatter(const int* __restrict__ ei,
                                                 int* __restrict__ cursor,
                                                 int2* __restrict__ csrp, int E0, int N)
{
    int e = blockIdx.x * 256 + threadIdx.x;
    int E = E0 + N;
    if (e >= E) return;
    int src, dst;
    if (e < E0) { src = ei[e]; dst = ei[E0 + e]; }
    else        { src = e - E0; dst = src; }
    int pos = atomicAdd(&cursor[dst], 1);
    csrp[pos] = make_int2(e, src);
}

// ---------------- fused per-node: logits + online softmax + aggregation + Wo ------------
// one wave per node; lane = h*8 + c
__global__ __launch_bounds__(256) void k_fused(
    const int2* __restrict__ csrp, const int* __restrict__ row,
    const unsigned short* __restrict__ tpnb, const float* __restrict__ q,
    const unsigned short* __restrict__ kb, const unsigned short* __restrict__ vb,
    const float* __restrict__ eattr,
    const float* __restrict__ an, const float* __restrict__ bn,
    const float* __restrict__ We, const float* __restrict__ comp_b,
    const float* __restrict__ Wo, const float* __restrict__ bo,
    float* __restrict__ out, int E0, int N)
{
    const int tid = threadIdx.x;
    const int wave = tid >> 6, lane = tid & 63;
    const int h = lane >> 3;
    const int n = blockIdx.x * 4 + wave;
    if (n >= N) return;

    // per-lane We row: wet[d] = We[lane][d]
    float wet[16];
    {
        const float4* wr = (const float4*)(We + (size_t)lane * 16);
        float4 w0 = wr[0], w1 = wr[1], w2 = wr[2], w3 = wr[3];
        wet[0]=w0.x;  wet[1]=w0.y;  wet[2]=w0.z;  wet[3]=w0.w;
        wet[4]=w1.x;  wet[5]=w1.y;  wet[6]=w1.z;  wet[7]=w1.w;
        wet[8]=w2.x;  wet[9]=w2.y;  wet[10]=w2.z; wet[11]=w2.w;
        wet[12]=w3.x; wet[13]=w3.y; wet[14]=w3.z; wet[15]=w3.w;
    }
    float wsum = 0.f;
    #pragma unroll
    for (int d = 0; d < 16; d++) wsum += wet[d];          // self-loop: ea = all ones

    const int beg = row[n], end = row[n + 1];
    const float qv = q[(size_t)n * 64 + lane] * 0.35355339059327373f;  // 1/sqrt(8) folded
    const float bnh = bn[(size_t)n * 8 + h] + comp_b[h];
    float td0 = 0.f, td1 = 0.f;
    if (lane < 48) {
        unsigned u = *(const unsigned*)(tpnb + (size_t)n * 96 + 2 * lane);
        td0 = __uint_as_float(u << 16)         * (-0.25f / 96.f);   // corr coeff folded
        td1 = __uint_as_float(u & 0xffff0000u) * (-0.25f / 96.f);
    }

    float mh = -1e30f, dsum = 0.f, acc = 0.f;

    int2 ec = csrp[beg];
    for (int idx = beg; idx < end; ++idx) {
        const int e = ec.x, s = ec.y;
        // gathers (src side)
        unsigned tsu = 0;
        if (lane < 48) tsu = *(const unsigned*)(tpnb + (size_t)s * 96 + 2 * lane);
        unsigned short ku = kb[(size_t)s * 64 + lane];
        unsigned short vu = vb[(size_t)s * 64 + lane];
        float anv = an[(size_t)s * 8 + h];
        if (idx + 1 < end) ec = csrp[idx + 1];   // prefetch next edge ids

        // wea = We[lane] . ea[e]  (wave-uniform edge -> scalar loads)
        float wea;
        const int eu = __builtin_amdgcn_readfirstlane(e);
        if (eu < E0) {
            const float4* ep = (const float4*)(eattr + (size_t)eu * 16);
            float4 e0 = ep[0], e1 = ep[1], e2 = ep[2], e3 = ep[3];
            float wa = e0.x*wet[0]  + e0.y*wet[1]  + e0.z*wet[2]  + e0.w*wet[3];
            float wb = e1.x*wet[4]  + e1.y*wet[5]  + e1.z*wet[6]  + e1.w*wet[7];
            float wc = e2.x*wet[8]  + e2.y*wet[9]  + e2.z*wet[10] + e2.w*wet[11];
            float wd = e3.x*wet[12] + e3.y*wet[13] + e3.z*wet[14] + e3.w*wet[15];
            wea = (wa + wb) + (wc + wd);
        } else {
            wea = wsum;
        }

        // tanh term (same value across the 8 lanes of group h)
        float ex = __expf(2.f * (anv + bnh));
        float t = 1.f - 2.f / (ex + 1.f);

        // column value: corr partial (coeff folded) + tanh partial (-t/256)
        float ts0 = __uint_as_float(tsu << 16);
        float ts1 = __uint_as_float(tsu & 0xffff0000u);
        float cv = ts0 * td0 + ts1 * td1 + t * (-1.f / 256.f);
        // cross-group (column) reduce first: each lane gets colsum + T
        cv += __shfl_xor(cv, 8); cv += __shfl_xor(cv, 16); cv += __shfl_xor(cv, 32);

        // qk + efk partial, then within-group reduce carries cv along
        float s1 = bf2f(ku) * (qv + wea) + cv;
        s1 += __shfl_xor(s1, 1); s1 += __shfl_xor(s1, 2); s1 += __shfl_xor(s1, 4);

        float a = fmaxf(s1, 0.2f * s1);            // leaky relu

        // online softmax update (per head, replicated across c)
        float mn = fmaxf(mh, a);
        float sc = __expf(mh - mn);
        float p = __expf(a - mn);
        dsum = dsum * sc + p;
        acc = acc * sc + p * bf2f(vu);
        mh = mn;
    }

    float outv = acc / (dsum + 1e-16f);

    // fused output projection: out[n][cp] = sum_hc outv[hc]*Wo[cp][hc] + bo[cp]
    float po[8];
    #pragma unroll
    for (int cp8 = 0; cp8 < 8; cp8++) po[cp8] = outv * Wo[cp8 * 64 + lane];
    #pragma unroll
    for (int m = 1; m < 64; m <<= 1) {
        #pragma unroll
        for (int cp8 = 0; cp8 < 8; cp8++) po[cp8] += __shfl_xor(po[cp8], m);
    }
    if (lane < 8) out[(size_t)n * 8 + lane] = po[lane] + bo[lane];
}

extern "C" void kernel_launch(void* const* d_in, const int* in_sizes, int n_in,
                              void* d_out, int out_size, void* d_ws, size_t ws_size,
                              hipStream_t stream)
{
    const float* x     = (const float*)d_in[0];
    const int*   ei    = (const int*)d_in[1];
    const float* eattr = (const float*)d_in[2];
    const float* tp    = (const float*)d_in[3];
    const float* Wq    = (const float*)d_in[4];
    const float* Wk    = (const float*)d_in[5];
    const float* Wv    = (const float*)d_in[6];
    const float* We    = (const float*)d_in[7];
    const float* compW = (const float*)d_in[8];
    const float* compb = (const float*)d_in[9];
    const float* Wo    = (const float*)d_in[10];
    const float* bo    = (const float*)d_in[11];
    float* out = (float*)d_out;

    const int N  = in_sizes[0] / 128;
    const int E0 = in_sizes[1] / 2;
    const int E  = E0 + N;
    const int NB = (N + 255) / 256;

    float* ws = (float*)d_ws;
    size_t off = 0;
    unsigned short* tpnb = (unsigned short*)(ws + off); off += (size_t)N * 48;   // N*96 ushort
    float* q  = ws + off; off += (size_t)N * 64;
    unsigned short* kb = (unsigned short*)(ws + off); off += (size_t)N * 32;     // N*64 ushort
    unsigned short* vb = (unsigned short*)(ws + off); off += (size_t)N * 32;
    float* an = ws + off; off += (size_t)N * 8;
    float* bn = ws + off; off += (size_t)N * 8;
    int* deg    = (int*)(ws + off); off += N;
    int* rowp   = (int*)(ws + off); off += N + 1;
    int* cursor = (int*)(ws + off); off += N;
    int* bsum   = (int*)(ws + off); off += 256;
    int2* csrp  = (int2*)(ws + off); off += (size_t)E * 2;

    hipMemsetAsync(deg, 0, (size_t)N * sizeof(int), stream);

    k_hist<<<(E + 255) / 256, 256, 0, stream>>>(ei, deg, E0, N);
    k_scanA<<<NB, 256, 0, stream>>>(deg, bsum, N);
    k_scanB<<<1, 256, 0, stream>>>(bsum, NB);
    k_scanC<<<NB, 256, 0, stream>>>(deg, bsum, rowp, cursor, N);
    k_scatter<<<(E + 255) / 256, 256, 0, stream>>>(ei, cursor, csrp, E0, N);

    k_proj<<<(N + 63) / 64, 256, 0, stream>>>(x, Wq, Wk, Wv, compW, q, kb, vb, an, bn, N);
    k_tpn<<<(N + 3) / 4, 256, 0, stream>>>(tp, tpnb, N);
    k_fused<<<(N + 3) / 4, 256, 0, stream>>>(csrp, rowp, tpnb, q, kb, vb, eattr, an, bn,
                                             We, compb, Wo, bo, out, E0, N);
}